// Round 7
// baseline (366.985 us; speedup 1.0000x reference)
//
#include <hip/hip_runtime.h>
#include <cmath>

typedef __bf16 bf16;
typedef __bf16 bf16x8 __attribute__((ext_vector_type(8)));
typedef __bf16 bf16x4 __attribute__((ext_vector_type(4)));
typedef float floatx4 __attribute__((ext_vector_type(4)));

#define MFMA16(A, B, C) __builtin_amdgcn_mfma_f32_16x16x32_bf16((A), (B), (C), 0, 0, 0)

// async 16B/lane global->LDS (lds dest = wave-uniform base + lane*16)
#define GLDS16(g, l)                                                   \
  __builtin_amdgcn_global_load_lds(                                    \
      (const __attribute__((address_space(1))) void*)(g),              \
      (__attribute__((address_space(3))) void*)(l), 16, 0, 0)

// ---------------------------------------------------------------------------
// fused: LN1 (blocks 0..8191) + fp32->bf16 weight convert (blocks 8192..)
// ---------------------------------------------------------------------------
__global__ __launch_bounds__(256) void pre_kernel(
    const float* __restrict__ x, const float* __restrict__ g,
    const float* __restrict__ be, bf16* __restrict__ h1,
    const float* __restrict__ s0, bf16* __restrict__ d0, int n0,
    const float* __restrict__ s1, bf16* __restrict__ d1, int n1,
    const float* __restrict__ s2, bf16* __restrict__ d2, int n2,
    const float* __restrict__ s3, bf16* __restrict__ d3, int n3) {
  int bid = blockIdx.x;
  int t = threadIdx.x;
  if (bid < 8192) {
    const float* xr = x + (size_t)bid * 768;
    float v0 = xr[t], v1 = xr[t + 256], v2 = xr[t + 512];
    float s = v0 + v1 + v2;
    float s2 = v0 * v0 + v1 * v1 + v2 * v2;
#pragma unroll
    for (int o = 1; o < 64; o <<= 1) {
      s += __shfl_xor(s, o, 64);
      s2 += __shfl_xor(s2, o, 64);
    }
    __shared__ float red[8];
    int w = t >> 6, lane = t & 63;
    if (lane == 0) { red[w] = s; red[4 + w] = s2; }
    __syncthreads();
    float ts = red[0] + red[1] + red[2] + red[3];
    float ts2 = red[4] + red[5] + red[6] + red[7];
    float mean = ts * (1.0f / 768.0f);
    float var = ts2 * (1.0f / 768.0f) - mean * mean;
    float rstd = rsqrtf(var + 1e-5f);
    bf16* orow = h1 + (size_t)bid * 768;
    orow[t]       = (bf16)((v0 - mean) * rstd * g[t]       + be[t]);
    orow[t + 256] = (bf16)((v1 - mean) * rstd * g[t + 256] + be[t + 256]);
    orow[t + 512] = (bf16)((v2 - mean) * rstd * g[t + 512] + be[t + 512]);
    return;
  }
  int i = (bid - 8192) * 256 + t;
  const float* s;
  bf16* d;
  if (i < n0) { s = s0 + (size_t)i * 4; d = d0 + (size_t)i * 4; }
  else if ((i -= n0) < n1) { s = s1 + (size_t)i * 4; d = d1 + (size_t)i * 4; }
  else if ((i -= n1) < n2) { s = s2 + (size_t)i * 4; d = d2 + (size_t)i * 4; }
  else if ((i -= n2) < n3) { s = s3 + (size_t)i * 4; d = d3 + (size_t)i * 4; }
  else return;
  bf16x4 v;
  v[0] = (bf16)s[0]; v[1] = (bf16)s[1]; v[2] = (bf16)s[2]; v[3] = (bf16)s[3];
  *(bf16x4*)d = v;
}

// ---------------------------------------------------------------------------
// LayerNorm over C=768, fp32 in -> bf16 out (x1 -> h2)
// ---------------------------------------------------------------------------
__global__ __launch_bounds__(256) void ln_kernel(const float* __restrict__ x,
                                                 const float* __restrict__ g,
                                                 const float* __restrict__ be,
                                                 bf16* __restrict__ out) {
  int row = blockIdx.x;
  int t = threadIdx.x;
  const float* xr = x + (size_t)row * 768;
  float v0 = xr[t], v1 = xr[t + 256], v2 = xr[t + 512];
  float s = v0 + v1 + v2;
  float s2 = v0 * v0 + v1 * v1 + v2 * v2;
#pragma unroll
  for (int o = 1; o < 64; o <<= 1) {
    s += __shfl_xor(s, o, 64);
    s2 += __shfl_xor(s2, o, 64);
  }
  __shared__ float red[8];
  int w = t >> 6, lane = t & 63;
  if (lane == 0) { red[w] = s; red[4 + w] = s2; }
  __syncthreads();
  float ts = red[0] + red[1] + red[2] + red[3];
  float ts2 = red[4] + red[5] + red[6] + red[7];
  float mean = ts * (1.0f / 768.0f);
  float var = ts2 * (1.0f / 768.0f) - mean * mean;
  float rstd = rsqrtf(var + 1e-5f);
  bf16* orow = out + (size_t)row * 768;
  orow[t]       = (bf16)((v0 - mean) * rstd * g[t]       + be[t]);
  orow[t + 256] = (bf16)((v1 - mean) * rstd * g[t + 256] + be[t + 256]);
  orow[t + 512] = (bf16)((v2 - mean) * rstd * g[t + 512] + be[t + 512]);
}

// ---------------------------------------------------------------------------
// GEMM: C[m,n] = sum_k A[m,k]*B[n,k] (+bias)  (A:[M,K] bf16, B:[N,K] bf16)
// 128 x (32*NJ) tile, 4 waves (each 64 x 16*NJ), BK=64, global_load_lds
// width=16 into XOR-granule-swizzled 64-elem rows (2-way ds_read, free).
// XCD swizzle: flat%8 = m-stripe, n fastest.
// ---------------------------------------------------------------------------
constexpr int EP_BF16 = 0;
constexpr int EP_RES_F32 = 1;
constexpr int EP_GELU_BF16 = 2;

template <int EP, int NJ>
__global__ __launch_bounds__(256, 3) void gemm_bt(
    const bf16* __restrict__ A, const bf16* __restrict__ Bw,
    const float* __restrict__ bias, const float* __restrict__ resid,
    void* __restrict__ outp, int M, int N, int K) {
  __shared__ alignas(16) bf16 Asl[128 * 64];
  __shared__ alignas(16) bf16 Bsl[NJ * 32 * 64];
  int tid = threadIdx.x;
  int lane = tid & 63, w = tid >> 6;
  int wm = w >> 1, wn = w & 1;
  int q16 = lane & 15, quad = lane >> 4;
  int fid = blockIdx.x + gridDim.x * blockIdx.y;
  int nb = gridDim.x;
  int s = fid >> 3;
  int m0 = ((fid & 7) * (gridDim.y >> 3) + s / nb) * 128;
  int n0 = (s % nb) * (NJ * 32);

  floatx4 acc[4][NJ];
#pragma unroll
  for (int i = 0; i < 4; i++)
#pragma unroll
    for (int j = 0; j < NJ; j++) acc[i][j] = (floatx4){0.f, 0.f, 0.f, 0.f};

  int rIn = lane >> 3;
  int cg = (lane & 7) ^ rIn;
  const bf16* ag[4];
  const bf16* bg[NJ];
#pragma unroll
  for (int q = 0; q < 4; q++)
    ag[q] = A + (size_t)(m0 + (w * 4 + q) * 8 + rIn) * K + cg * 8;
#pragma unroll
  for (int q = 0; q < NJ; q++)
    bg[q] = Bw + (size_t)(n0 + (w * NJ + q) * 8 + rIn) * K + cg * 8;
  bf16* la = &Asl[w * 2048];
  bf16* lb = &Bsl[w * NJ * 512];

  int msel = q16 & 7;
  int offA[2][4], offB[2][NJ];
#pragma unroll
  for (int ks = 0; ks < 2; ks++) {
#pragma unroll
    for (int i = 0; i < 4; i++)
      offA[ks][i] = (wm * 64 + i * 16 + q16) * 64 + (((ks * 4 + quad) ^ msel)) * 8;
#pragma unroll
    for (int j = 0; j < NJ; j++)
      offB[ks][j] = (wn * 16 * NJ + j * 16 + q16) * 64 + (((ks * 4 + quad) ^ msel)) * 8;
  }

  for (int k0 = 0; k0 < K; k0 += 64) {
    __syncthreads();
#pragma unroll
    for (int q = 0; q < 4; q++) {
      GLDS16(ag[q], la + q * 512);
      ag[q] += 64;
    }
#pragma unroll
    for (int q = 0; q < NJ; q++) {
      GLDS16(bg[q], lb + q * 512);
      bg[q] += 64;
    }
    __syncthreads();
#pragma unroll
    for (int ks = 0; ks < 2; ks++) {
      bf16x8 af[4], bfr[NJ];
#pragma unroll
      for (int i = 0; i < 4; i++) af[i] = *(const bf16x8*)&Asl[offA[ks][i]];
#pragma unroll
      for (int j = 0; j < NJ; j++) bfr[j] = *(const bf16x8*)&Bsl[offB[ks][j]];
#pragma unroll
      for (int i = 0; i < 4; i++)
#pragma unroll
        for (int j = 0; j < NJ; j++) acc[i][j] = MFMA16(af[i], bfr[j], acc[i][j]);
    }
  }

#pragma unroll
  for (int i = 0; i < 4; i++) {
#pragma unroll
    for (int j = 0; j < NJ; j++) {
#pragma unroll
      for (int r = 0; r < 4; r++) {
        int m = m0 + wm * 64 + i * 16 + quad * 4 + r;
        int n = n0 + wn * 16 * NJ + j * 16 + q16;
        size_t idx = (size_t)m * N + n;
        float v = acc[i][j][r] + bias[n];
        if constexpr (EP == EP_BF16) {
          ((bf16*)outp)[idx] = (bf16)v;
        } else if constexpr (EP == EP_RES_F32) {
          ((float*)outp)[idx] = v + resid[idx];
        } else {
          float u = v * (2.3022083f + 0.1029443f * v * v);
          float e = __builtin_amdgcn_exp2f(-u);
          float gv = v * __builtin_amdgcn_rcpf(1.0f + e);
          ((bf16*)outp)[idx] = (bf16)gv;
        }
      }
    }
  }
}

// ---------------------------------------------------------------------------
// V transpose: qkv[b,key,2,h,d] -> VT[b,h,d,key]  (12.6 MB, one-shot)
// 64key x 64d tile per block via padded LDS (pad 74 -> <=2-way on scatter).
// ---------------------------------------------------------------------------
__global__ __launch_bounds__(256) void vt_kernel(const bf16* __restrict__ qkv,
                                                 bf16* __restrict__ VT) {
  __shared__ bf16 T[64 * 74];
  int t = threadIdx.x;
  int bh = blockIdx.y;
  int b = bh / 12, h = bh % 12;
  int kt = blockIdx.x;                 // 64-key tile
  int kloc = t >> 2;
  int d0 = (t & 3) * 16;
  const bf16* src = qkv + (size_t)(b * 1024 + kt * 64 + kloc) * 2304 + 1536 +
                    h * 64 + d0;
  bf16x8 a = *(const bf16x8*)src;
  bf16x8 c = *(const bf16x8*)(src + 8);
#pragma unroll
  for (int e = 0; e < 8; e++) T[(d0 + e) * 74 + kloc] = a[e];
#pragma unroll
  for (int e = 0; e < 8; e++) T[(d0 + 8 + e) * 74 + kloc] = c[e];
  __syncthreads();
  int d = t >> 2;
  int k0 = (t & 3) * 16;
  bf16x8 r0, r1;
#pragma unroll
  for (int e = 0; e < 8; e++) r0[e] = T[d * 74 + k0 + e];
#pragma unroll
  for (int e = 0; e < 8; e++) r1[e] = T[d * 74 + k0 + 8 + e];
  bf16* dst = VT + ((size_t)bh * 64 + d) * 1024 + kt * 64 + k0;
  *(bf16x8*)dst = r0;
  *(bf16x8*)(dst + 8) = r1;
}

// ---------------------------------------------------------------------------
// Flash attention v4: WAVE-AUTONOMOUS (zero __syncthreads).
// K and V^T are loaded straight from global into MFMA B-operand layout
// (lane n = row, quad*8 = k-offset -> one 16B load per lane per frag).
// Only P round-trips through per-wave LDS (same-wave lgkm ordering).
// Latency hidden by 12 independent waves/CU, no barrier drains.
// No-max softmax: |s|=|q.k|/8 small -> exp overflow-safe, shift-invariant.
// ---------------------------------------------------------------------------
__global__ __launch_bounds__(256, 4) void attn_kernel(const bf16* __restrict__ qkv,
                                                      const bf16* __restrict__ VT,
                                                      bf16* __restrict__ o) {
  __shared__ alignas(16) bf16 Pl[4][2][16 * 40];  // per-wave P, pad 40
  int tid = threadIdx.x;
  int lane = tid & 63, w = tid >> 6;
  int q16 = lane & 15, quad = lane >> 4;
  int bh = blockIdx.y;
  int b = bh / 12, h = bh % 12;
  int qbase = blockIdx.x * 128 + w * 32;
  const int KS = 32 * 2304;

  // Q fragments (A-layout m=q16, k=quad*8+j), 2 q-tiles x 2 k-chunks
  bf16x8 qf[2][2];
#pragma unroll
  for (int qt = 0; qt < 2; qt++)
#pragma unroll
    for (int c = 0; c < 2; c++)
      qf[qt][c] = *(const bf16x8*)(qkv +
          (size_t)(b * 1024 + qbase + qt * 16 + q16) * 2304 + h * 64 +
          c * 32 + quad * 8);

  // K direct-load pointers: kf[nc][ck] = K[key=nc*16+q16][d=ck*32+quad*8 ..+7]
  const bf16* kp[2];
#pragma unroll
  for (int nc = 0; nc < 2; nc++)
    kp[nc] = qkv + (size_t)(b * 1024 + nc * 16 + q16) * 2304 + 768 + h * 64 +
             quad * 8;
  // V^T direct-load pointers: vf[dc] = VT[bh][d=dc*16+q16][key=quad*8 ..+7]
  const bf16* vp[4];
#pragma unroll
  for (int dc = 0; dc < 4; dc++)
    vp[dc] = VT + ((size_t)bh * 64 + dc * 16 + q16) * 1024 + quad * 8;

  const bf16* pread = &Pl[w][0][q16 * 40 + quad * 8];
  int pw_base = (quad * 4) * 40 + q16;

  float l_[2][4];
  floatx4 oacc[2][4];
#pragma unroll
  for (int qt = 0; qt < 2; qt++)
#pragma unroll
    for (int r = 0; r < 4; r++) l_[qt][r] = 0.f;
#pragma unroll
  for (int qt = 0; qt < 2; qt++)
#pragma unroll
    for (int dc = 0; dc < 4; dc++) oacc[qt][dc] = (floatx4){0.f, 0.f, 0.f, 0.f};

  for (int kt = 0; kt < 32; kt++) {
    // issue all global loads up front (K for S, V for PV) -- no LDS staging
    bf16x8 kf[2][2];
#pragma unroll
    for (int nc = 0; nc < 2; nc++) {
#pragma unroll
      for (int ck = 0; ck < 2; ck++)
        kf[nc][ck] = *(const bf16x8*)(kp[nc] + ck * 32);
      kp[nc] += KS;
    }
    bf16x8 vf[4];
#pragma unroll
    for (int dc = 0; dc < 4; dc++) {
      vf[dc] = *(const bf16x8*)vp[dc];
      vp[dc] += 32;
    }

    // S = Q K^T (2 chunks of 16 keys), exp, P -> per-wave LDS
#pragma unroll
    for (int qt = 0; qt < 2; qt++) {
#pragma unroll
      for (int nc = 0; nc < 2; nc++) {
        floatx4 z = (floatx4){0.f, 0.f, 0.f, 0.f};
        z = MFMA16(qf[qt][0], kf[nc][0], z);
        z = MFMA16(qf[qt][1], kf[nc][1], z);
#pragma unroll
        for (int r = 0; r < 4; r++) {
          float p = __builtin_amdgcn_exp2f(z[r] * 0.18033688011f);
          l_[qt][r] += p;
          Pl[w][qt][pw_base + r * 40 + nc * 16] = (bf16)p;
        }
      }
    }
    // no barrier: P is per-wave; same-wave ds ordering suffices

#pragma unroll
    for (int qt = 0; qt < 2; qt++) {
      bf16x8 pf = *(const bf16x8*)(pread + qt * 640);
#pragma unroll
      for (int dc = 0; dc < 4; dc++)
        oacc[qt][dc] = MFMA16(pf, vf[dc], oacc[qt][dc]);
    }
  }

  // final: reduce l over the 16 lanes of each quad-group, divide, store
#pragma unroll
  for (int qt = 0; qt < 2; qt++) {
    bf16* op = o + (size_t)(b * 1024 + qbase + qt * 16) * 768 + h * 64;
#pragma unroll
    for (int r = 0; r < 4; r++) {
      float s = l_[qt][r];
#pragma unroll
      for (int off = 1; off < 16; off <<= 1) s += __shfl_xor(s, off, 16);
      float inv = 1.0f / s;
#pragma unroll
      for (int dc = 0; dc < 4; dc++)
        op[(size_t)(quad * 4 + r) * 768 + dc * 16 + q16] =
            (bf16)(oacc[qt][dc][r] * inv);
    }
  }
}

// ---------------------------------------------------------------------------
extern "C" void kernel_launch(void* const* d_in, const int* in_sizes, int n_in,
                              void* d_out, int out_size, void* d_ws, size_t ws_size,
                              hipStream_t stream) {
  (void)in_sizes; (void)n_in; (void)out_size; (void)ws_size;
  const float* x      = (const float*)d_in[0];
  const float* ln1_w  = (const float*)d_in[1];
  const float* ln1_b  = (const float*)d_in[2];
  const float* qkv_w  = (const float*)d_in[3];
  const float* qkv_b  = (const float*)d_in[4];
  const float* proj_w = (const float*)d_in[5];
  const float* proj_b = (const float*)d_in[6];
  const float* ln2_w  = (const float*)d_in[7];
  const float* ln2_b  = (const float*)d_in[8];
  const float* fc1_w  = (const float*)d_in[9];
  const float* fc1_b  = (const float*)d_in[10];
  const float* fc2_w  = (const float*)d_in[11];
  const float* fc2_b  = (const float*)d_in[12];

  char* ws = (char*)d_ws;
  size_t off = 0;
  auto alloc = [&](size_t bytes) {
    void* p = ws + off;
    off += (bytes + 255) & ~(size_t)255;
    return p;
  };
  bf16* wq  = (bf16*)alloc((size_t)2304 * 768 * 2);
  bf16* wp  = (bf16*)alloc((size_t)768 * 768 * 2);
  bf16* wf1 = (bf16*)alloc((size_t)3072 * 768 * 2);
  bf16* wf2 = (bf16*)alloc((size_t)768 * 3072 * 2);
  bf16* slotA = (bf16*)alloc((size_t)8192 * 768 * 2);   // h1 / ob / h2
  bf16* slotB = (bf16*)alloc((size_t)8192 * 3072 * 2);  // qkv / fc1-out
  float* x1 = (float*)alloc((size_t)8192 * 768 * 4);
  bf16* VT = (bf16*)alloc((size_t)96 * 64 * 1024 * 2);  // V transposed

  bf16* h1 = slotA;
  bf16* qkvb = slotB;
  bf16* ob = slotA;
  bf16* h2 = slotA;
  bf16* hm = slotB;

  pre_kernel<<<8192 + 6912, 256, 0, stream>>>(
      x, ln1_w, ln1_b, h1,
      qkv_w, wq, 2304 * 768 / 4, proj_w, wp, 768 * 768 / 4,
      fc1_w, wf1, 3072 * 768 / 4, fc2_w, wf2, 768 * 3072 / 4);

  gemm_bt<EP_BF16, 4><<<dim3(18, 64), 256, 0, stream>>>(
      h1, wq, qkv_b, nullptr, qkvb, 8192, 2304, 768);
  vt_kernel<<<dim3(16, 96), 256, 0, stream>>>(qkvb, VT);
  attn_kernel<<<dim3(8, 96), 256, 0, stream>>>(qkvb, VT, ob);
  gemm_bt<EP_RES_F32, 2><<<dim3(12, 64), 256, 0, stream>>>(
      ob, wp, proj_b, x, x1, 8192, 768, 768);
  ln_kernel<<<8192, 256, 0, stream>>>(x1, ln2_w, ln2_b, h2);
  gemm_bt<EP_GELU_BF16, 4><<<dim3(24, 64), 256, 0, stream>>>(
      h2, wf1, fc1_b, nullptr, hm, 8192, 3072, 768);
  gemm_bt<EP_RES_F32, 2><<<dim3(12, 64), 256, 0, stream>>>(
      hm, wf2, fc2_b, x1, (float*)d_out, 8192, 768, 3072);
}

// Round 8
// 340.704 us; speedup vs baseline: 1.0771x; 1.0771x over previous
//
#include <hip/hip_runtime.h>
#include <cmath>

typedef __bf16 bf16;
typedef __bf16 bf16x8 __attribute__((ext_vector_type(8)));
typedef __bf16 bf16x4 __attribute__((ext_vector_type(4)));
typedef float floatx4 __attribute__((ext_vector_type(4)));
typedef short short4v __attribute__((ext_vector_type(4)));

#define MFMA16(A, B, C) __builtin_amdgcn_mfma_f32_16x16x32_bf16((A), (B), (C), 0, 0, 0)

static __device__ __forceinline__ floatx4 mfma_k16(bf16x4 a, bf16x4 b, floatx4 c) {
  return __builtin_amdgcn_mfma_f32_16x16x16bf16_1k(
      __builtin_bit_cast(short4v, a), __builtin_bit_cast(short4v, b), c, 0, 0, 0);
}

// async 16B/lane global->LDS (lds dest = wave-uniform base + lane*16)
#define GLDS16(g, l)                                                   \
  __builtin_amdgcn_global_load_lds(                                    \
      (const __attribute__((address_space(1))) void*)(g),              \
      (__attribute__((address_space(3))) void*)(l), 16, 0, 0)

// ---------------------------------------------------------------------------
// fused: LN1 (blocks 0..8191) + fp32->bf16 weight convert (blocks 8192..)
// ---------------------------------------------------------------------------
__global__ __launch_bounds__(256) void pre_kernel(
    const float* __restrict__ x, const float* __restrict__ g,
    const float* __restrict__ be, bf16* __restrict__ h1,
    const float* __restrict__ s0, bf16* __restrict__ d0, int n0,
    const float* __restrict__ s1, bf16* __restrict__ d1, int n1,
    const float* __restrict__ s2, bf16* __restrict__ d2, int n2,
    const float* __restrict__ s3, bf16* __restrict__ d3, int n3) {
  int bid = blockIdx.x;
  int t = threadIdx.x;
  if (bid < 8192) {
    const float* xr = x + (size_t)bid * 768;
    float v0 = xr[t], v1 = xr[t + 256], v2 = xr[t + 512];
    float s = v0 + v1 + v2;
    float s2 = v0 * v0 + v1 * v1 + v2 * v2;
#pragma unroll
    for (int o = 1; o < 64; o <<= 1) {
      s += __shfl_xor(s, o, 64);
      s2 += __shfl_xor(s2, o, 64);
    }
    __shared__ float red[8];
    int w = t >> 6, lane = t & 63;
    if (lane == 0) { red[w] = s; red[4 + w] = s2; }
    __syncthreads();
    float ts = red[0] + red[1] + red[2] + red[3];
    float ts2 = red[4] + red[5] + red[6] + red[7];
    float mean = ts * (1.0f / 768.0f);
    float var = ts2 * (1.0f / 768.0f) - mean * mean;
    float rstd = rsqrtf(var + 1e-5f);
    bf16* orow = h1 + (size_t)bid * 768;
    orow[t]       = (bf16)((v0 - mean) * rstd * g[t]       + be[t]);
    orow[t + 256] = (bf16)((v1 - mean) * rstd * g[t + 256] + be[t + 256]);
    orow[t + 512] = (bf16)((v2 - mean) * rstd * g[t + 512] + be[t + 512]);
    return;
  }
  int i = (bid - 8192) * 256 + t;
  const float* s;
  bf16* d;
  if (i < n0) { s = s0 + (size_t)i * 4; d = d0 + (size_t)i * 4; }
  else if ((i -= n0) < n1) { s = s1 + (size_t)i * 4; d = d1 + (size_t)i * 4; }
  else if ((i -= n1) < n2) { s = s2 + (size_t)i * 4; d = d2 + (size_t)i * 4; }
  else if ((i -= n2) < n3) { s = s3 + (size_t)i * 4; d = d3 + (size_t)i * 4; }
  else return;
  bf16x4 v;
  v[0] = (bf16)s[0]; v[1] = (bf16)s[1]; v[2] = (bf16)s[2]; v[3] = (bf16)s[3];
  *(bf16x4*)d = v;
}

// ---------------------------------------------------------------------------
// LayerNorm over C=768, fp32 in -> bf16 out (x1 -> h2)
// ---------------------------------------------------------------------------
__global__ __launch_bounds__(256) void ln_kernel(const float* __restrict__ x,
                                                 const float* __restrict__ g,
                                                 const float* __restrict__ be,
                                                 bf16* __restrict__ out) {
  int row = blockIdx.x;
  int t = threadIdx.x;
  const float* xr = x + (size_t)row * 768;
  float v0 = xr[t], v1 = xr[t + 256], v2 = xr[t + 512];
  float s = v0 + v1 + v2;
  float s2 = v0 * v0 + v1 * v1 + v2 * v2;
#pragma unroll
  for (int o = 1; o < 64; o <<= 1) {
    s += __shfl_xor(s, o, 64);
    s2 += __shfl_xor(s2, o, 64);
  }
  __shared__ float red[8];
  int w = t >> 6, lane = t & 63;
  if (lane == 0) { red[w] = s; red[4 + w] = s2; }
  __syncthreads();
  float ts = red[0] + red[1] + red[2] + red[3];
  float ts2 = red[4] + red[5] + red[6] + red[7];
  float mean = ts * (1.0f / 768.0f);
  float var = ts2 * (1.0f / 768.0f) - mean * mean;
  float rstd = rsqrtf(var + 1e-5f);
  bf16* orow = out + (size_t)row * 768;
  orow[t]       = (bf16)((v0 - mean) * rstd * g[t]       + be[t]);
  orow[t + 256] = (bf16)((v1 - mean) * rstd * g[t + 256] + be[t + 256]);
  orow[t + 512] = (bf16)((v2 - mean) * rstd * g[t + 512] + be[t + 512]);
}

// ---------------------------------------------------------------------------
// GEMM: C[m,n] = sum_k A[m,k]*B[n,k] (+bias)  (A:[M,K] bf16, B:[N,K] bf16)
// 128 x (32*NJ) tile, 4 waves, BK=64, global_load_lds width=16 into
// XOR-granule-swizzled 64-elem rows (2-way ds_read, free). XCD m-stripe.
// ---------------------------------------------------------------------------
constexpr int EP_BF16 = 0;
constexpr int EP_RES_F32 = 1;
constexpr int EP_GELU_BF16 = 2;

template <int EP, int NJ>
__global__ __launch_bounds__(256, 3) void gemm_bt(
    const bf16* __restrict__ A, const bf16* __restrict__ Bw,
    const float* __restrict__ bias, const float* __restrict__ resid,
    void* __restrict__ outp, int M, int N, int K) {
  __shared__ alignas(16) bf16 Asl[128 * 64];
  __shared__ alignas(16) bf16 Bsl[NJ * 32 * 64];
  int tid = threadIdx.x;
  int lane = tid & 63, w = tid >> 6;
  int wm = w >> 1, wn = w & 1;
  int q16 = lane & 15, quad = lane >> 4;
  int fid = blockIdx.x + gridDim.x * blockIdx.y;
  int nb = gridDim.x;
  int s = fid >> 3;
  int m0 = ((fid & 7) * (gridDim.y >> 3) + s / nb) * 128;
  int n0 = (s % nb) * (NJ * 32);

  floatx4 acc[4][NJ];
#pragma unroll
  for (int i = 0; i < 4; i++)
#pragma unroll
    for (int j = 0; j < NJ; j++) acc[i][j] = (floatx4){0.f, 0.f, 0.f, 0.f};

  int rIn = lane >> 3;
  int cg = (lane & 7) ^ rIn;
  const bf16* ag[4];
  const bf16* bg[NJ];
#pragma unroll
  for (int q = 0; q < 4; q++)
    ag[q] = A + (size_t)(m0 + (w * 4 + q) * 8 + rIn) * K + cg * 8;
#pragma unroll
  for (int q = 0; q < NJ; q++)
    bg[q] = Bw + (size_t)(n0 + (w * NJ + q) * 8 + rIn) * K + cg * 8;
  bf16* la = &Asl[w * 2048];
  bf16* lb = &Bsl[w * NJ * 512];

  int msel = q16 & 7;
  int offA[2][4], offB[2][NJ];
#pragma unroll
  for (int ks = 0; ks < 2; ks++) {
#pragma unroll
    for (int i = 0; i < 4; i++)
      offA[ks][i] = (wm * 64 + i * 16 + q16) * 64 + (((ks * 4 + quad) ^ msel)) * 8;
#pragma unroll
    for (int j = 0; j < NJ; j++)
      offB[ks][j] = (wn * 16 * NJ + j * 16 + q16) * 64 + (((ks * 4 + quad) ^ msel)) * 8;
  }

  for (int k0 = 0; k0 < K; k0 += 64) {
    __syncthreads();
#pragma unroll
    for (int q = 0; q < 4; q++) {
      GLDS16(ag[q], la + q * 512);
      ag[q] += 64;
    }
#pragma unroll
    for (int q = 0; q < NJ; q++) {
      GLDS16(bg[q], lb + q * 512);
      bg[q] += 64;
    }
    __syncthreads();
#pragma unroll
    for (int ks = 0; ks < 2; ks++) {
      bf16x8 af[4], bfr[NJ];
#pragma unroll
      for (int i = 0; i < 4; i++) af[i] = *(const bf16x8*)&Asl[offA[ks][i]];
#pragma unroll
      for (int j = 0; j < NJ; j++) bfr[j] = *(const bf16x8*)&Bsl[offB[ks][j]];
#pragma unroll
      for (int i = 0; i < 4; i++)
#pragma unroll
        for (int j = 0; j < NJ; j++) acc[i][j] = MFMA16(af[i], bfr[j], acc[i][j]);
    }
  }

#pragma unroll
  for (int i = 0; i < 4; i++) {
#pragma unroll
    for (int j = 0; j < NJ; j++) {
#pragma unroll
      for (int r = 0; r < 4; r++) {
        int m = m0 + wm * 64 + i * 16 + quad * 4 + r;
        int n = n0 + wn * 16 * NJ + j * 16 + q16;
        size_t idx = (size_t)m * N + n;
        float v = acc[i][j][r] + bias[n];
        if constexpr (EP == EP_BF16) {
          ((bf16*)outp)[idx] = (bf16)v;
        } else if constexpr (EP == EP_RES_F32) {
          ((float*)outp)[idx] = v + resid[idx];
        } else {
          float u = v * (2.3022083f + 0.1029443f * v * v);
          float e = __builtin_amdgcn_exp2f(-u);
          float gv = v * __builtin_amdgcn_rcpf(1.0f + e);
          ((bf16*)outp)[idx] = (bf16)gv;
        }
      }
    }
  }
}

// ---------------------------------------------------------------------------
// V transpose: qkv[b,key,2,h,d] -> VT[b,h,d,key]  (12.6 MB, one-shot)
// ---------------------------------------------------------------------------
__global__ __launch_bounds__(256) void vt_kernel(const bf16* __restrict__ qkv,
                                                 bf16* __restrict__ VT) {
  __shared__ bf16 T[64 * 74];
  int t = threadIdx.x;
  int bh = blockIdx.y;
  int b = bh / 12, h = bh % 12;
  int kt = blockIdx.x;                 // 64-key tile
  int kloc = t >> 2;
  int d0 = (t & 3) * 16;
  const bf16* src = qkv + (size_t)(b * 1024 + kt * 64 + kloc) * 2304 + 1536 +
                    h * 64 + d0;
  bf16x8 a = *(const bf16x8*)src;
  bf16x8 c = *(const bf16x8*)(src + 8);
#pragma unroll
  for (int e = 0; e < 8; e++) T[(d0 + e) * 74 + kloc] = a[e];
#pragma unroll
  for (int e = 0; e < 8; e++) T[(d0 + 8 + e) * 74 + kloc] = c[e];
  __syncthreads();
  int d = t >> 2;
  int k0 = (t & 3) * 16;
  bf16x8 r0, r1;
#pragma unroll
  for (int e = 0; e < 8; e++) r0[e] = T[d * 74 + k0 + e];
#pragma unroll
  for (int e = 0; e < 8; e++) r1[e] = T[d * 74 + k0 + 8 + e];
  bf16* dst = VT + ((size_t)bh * 64 + d) * 1024 + kt * 64 + k0;
  *(bf16x8*)dst = r0;
  *(bf16x8*)(dst + 8) = r1;
}

// ---------------------------------------------------------------------------
// Flash attention v5: operand-swapped, P never leaves registers.
// S^T = MFMA(A=K, B=Q): lane holds col=q(lane&15), rows=keys quad*4+r.
// exp'd values are EXACTLY the B-operand layout of mfma_16x16x16 (n=lane&15,
// k=quad*4+j) -> PV uses mfma_f32_16x16x16bf16_1k with A=V^T (staged via
// global_load_lds from the precomputed VT), B=pfrag (in-register). Output is
// O^T (rows=d=quad*4+r, cols=q) -> 8B vector stores. l is one scalar/lane.
// K/V^T double-buffered, single barrier per 32-key tile (R6 pattern).
// XCD pin: block f -> batch b = f&7 (K/V of one batch stays in one L2).
// No-max softmax: |s|=|q.k|/8 small -> exp overflow-safe, shift-invariant.
// ---------------------------------------------------------------------------
__global__ __launch_bounds__(256, 4) void attn_kernel(const bf16* __restrict__ qkv,
                                                      const bf16* __restrict__ VT,
                                                      bf16* __restrict__ o) {
  __shared__ alignas(16) bf16 Kl[2][32 * 64];   // [buf][key][d] XOR-swizzled
  __shared__ alignas(16) bf16 Vl[2][64 * 32];   // [buf] V^T tile, row-major
  int tid = threadIdx.x;
  int lane = tid & 63, w = tid >> 6;
  int q16 = lane & 15, quad = lane >> 4;
  int f = blockIdx.x;
  int b = f & 7, idx = f >> 3;
  int h = idx % 12;
  int qbase = (idx / 12) * 128 + w * 32;
  const int KS = 32 * 2304;

  // Q fragments (B-layout n=q16, k=quad*8+j), 2 q-tiles x 2 k-chunks
  bf16x8 qf[2][2];
#pragma unroll
  for (int qt = 0; qt < 2; qt++)
#pragma unroll
    for (int c = 0; c < 2; c++)
      qf[qt][c] = *(const bf16x8*)(qkv +
          (size_t)(b * 1024 + qbase + qt * 16 + q16) * 2304 + h * 64 +
          c * 32 + quad * 8);

  // K DMA: wave w stages keys w*8..w*8+7 at swizzled granule key*8+(c^(key&7))
  int kkey = w * 8 + (lane >> 3);
  int kchunk = (lane & 7) ^ (lane >> 3);
  const bf16* kg = qkv + (size_t)(b * 1024 + kkey) * 2304 + 768 + h * 64 +
                   kchunk * 8;
  bf16* kd[2] = {&Kl[0][w * 512], &Kl[1][w * 512]};

  // V^T DMA: wave w stages d-rows w*16..w*16+15; lane -> (d=w*16+(L>>2),
  // key-chunk c=L&3); granule = d_local*4 + c within wave's 1KB
  const bf16* vg = VT + ((size_t)(b * 12 + h) * 64 + w * 16 + (lane >> 2)) * 1024 +
                   (lane & 3) * 8;
  bf16* vd[2] = {&Vl[0][w * 512], &Vl[1][w * 512]};

  // K frag read offsets (A-operand, key=nc*16+q16, k=ck*32+quad*8)
  int koff[2][2];
#pragma unroll
  for (int nc = 0; nc < 2; nc++)
#pragma unroll
    for (int ck = 0; ck < 2; ck++) {
      int key = nc * 16 + q16;
      koff[nc][ck] = (key * 8 + ((ck * 4 + quad) ^ (key & 7))) * 8;
    }
  // V^T frag read offsets (b64: d=dc*16+q16, keys nc*16+quad*4..+3)
  int voff[4][2];
#pragma unroll
  for (int dc = 0; dc < 4; dc++)
#pragma unroll
    for (int nc = 0; nc < 2; nc++)
      voff[dc][nc] = (dc * 64 + q16 * 4 + nc * 2 + (quad >> 1)) * 8 + (quad & 1) * 4;

  float l_[2] = {0.f, 0.f};
  floatx4 oacc[2][4];
#pragma unroll
  for (int qt = 0; qt < 2; qt++)
#pragma unroll
    for (int dc = 0; dc < 4; dc++) oacc[qt][dc] = (floatx4){0.f, 0.f, 0.f, 0.f};

  // prologue: stage tile 0
  GLDS16(kg, kd[0]);
  kg += KS;
  GLDS16(vg, vd[0]);
  vg += 32;

  for (int kt = 0; kt < 32; kt++) {
    int cur = kt & 1, nxt = cur ^ 1;
    __syncthreads();  // buf[cur] staged & visible; buf[nxt] free for reuse
    if (kt < 31) {
      GLDS16(kg, kd[nxt]);   // in flight during compute below
      kg += KS;
      GLDS16(vg, vd[nxt]);
      vg += 32;
    }

    bf16x8 kf[2][2];
#pragma unroll
    for (int nc = 0; nc < 2; nc++)
#pragma unroll
      for (int ck = 0; ck < 2; ck++)
        kf[nc][ck] = *(const bf16x8*)&Kl[cur][koff[nc][ck]];
    bf16x4 vf[4][2];
#pragma unroll
    for (int dc = 0; dc < 4; dc++)
#pragma unroll
      for (int nc = 0; nc < 2; nc++)
        vf[dc][nc] = *(const bf16x4*)&Vl[cur][voff[dc][nc]];

#pragma unroll
    for (int qt = 0; qt < 2; qt++) {
#pragma unroll
      for (int nc = 0; nc < 2; nc++) {
        floatx4 z = (floatx4){0.f, 0.f, 0.f, 0.f};
        z = MFMA16(kf[nc][0], qf[qt][0], z);   // S^T: rows=keys, cols=q
        z = MFMA16(kf[nc][1], qf[qt][1], z);
        bf16x4 pfrag;
        float psum = 0.f;
#pragma unroll
        for (int r = 0; r < 4; r++) {
          float p = __builtin_amdgcn_exp2f(z[r] * 0.18033688011f);
          psum += p;
          pfrag[r] = (bf16)p;
        }
        l_[qt] += psum;
#pragma unroll
        for (int dc = 0; dc < 4; dc++)
          oacc[qt][dc] = mfma_k16(vf[dc][nc], pfrag, oacc[qt][dc]);
      }
    }
  }

  // final: l = sum over the 4 quad-copies of this q; divide; vector store
#pragma unroll
  for (int qt = 0; qt < 2; qt++) {
    float s = l_[qt];
    s += __shfl_xor(s, 16, 64);
    s += __shfl_xor(s, 32, 64);
    float inv = 1.0f / s;
    bf16* op = o + (size_t)(b * 1024 + qbase + qt * 16 + q16) * 768 + h * 64 +
               quad * 4;
#pragma unroll
    for (int dc = 0; dc < 4; dc++) {
      bf16x4 ov;
#pragma unroll
      for (int r = 0; r < 4; r++) ov[r] = (bf16)(oacc[qt][dc][r] * inv);
      *(bf16x4*)(op + dc * 16) = ov;
    }
  }
}

// ---------------------------------------------------------------------------
extern "C" void kernel_launch(void* const* d_in, const int* in_sizes, int n_in,
                              void* d_out, int out_size, void* d_ws, size_t ws_size,
                              hipStream_t stream) {
  (void)in_sizes; (void)n_in; (void)out_size; (void)ws_size;
  const float* x      = (const float*)d_in[0];
  const float* ln1_w  = (const float*)d_in[1];
  const float* ln1_b  = (const float*)d_in[2];
  const float* qkv_w  = (const float*)d_in[3];
  const float* qkv_b  = (const float*)d_in[4];
  const float* proj_w = (const float*)d_in[5];
  const float* proj_b = (const float*)d_in[6];
  const float* ln2_w  = (const float*)d_in[7];
  const float* ln2_b  = (const float*)d_in[8];
  const float* fc1_w  = (const float*)d_in[9];
  const float* fc1_b  = (const float*)d_in[10];
  const float* fc2_w  = (const float*)d_in[11];
  const float* fc2_b  = (const float*)d_in[12];

  char* ws = (char*)d_ws;
  size_t off = 0;
  auto alloc = [&](size_t bytes) {
    void* p = ws + off;
    off += (bytes + 255) & ~(size_t)255;
    return p;
  };
  bf16* wq  = (bf16*)alloc((size_t)2304 * 768 * 2);
  bf16* wp  = (bf16*)alloc((size_t)768 * 768 * 2);
  bf16* wf1 = (bf16*)alloc((size_t)3072 * 768 * 2);
  bf16* wf2 = (bf16*)alloc((size_t)768 * 3072 * 2);
  bf16* slotA = (bf16*)alloc((size_t)8192 * 768 * 2);   // h1 / ob / h2
  bf16* slotB = (bf16*)alloc((size_t)8192 * 3072 * 2);  // qkv / fc1-out
  float* x1 = (float*)alloc((size_t)8192 * 768 * 4);
  bf16* VT = (bf16*)alloc((size_t)96 * 64 * 1024 * 2);  // V transposed

  bf16* h1 = slotA;
  bf16* qkvb = slotB;
  bf16* ob = slotA;
  bf16* h2 = slotA;
  bf16* hm = slotB;

  pre_kernel<<<8192 + 6912, 256, 0, stream>>>(
      x, ln1_w, ln1_b, h1,
      qkv_w, wq, 2304 * 768 / 4, proj_w, wp, 768 * 768 / 4,
      fc1_w, wf1, 3072 * 768 / 4, fc2_w, wf2, 768 * 3072 / 4);

  gemm_bt<EP_BF16, 4><<<dim3(18, 64), 256, 0, stream>>>(
      h1, wq, qkv_b, nullptr, qkvb, 8192, 2304, 768);
  vt_kernel<<<dim3(16, 96), 256, 0, stream>>>(qkvb, VT);
  attn_kernel<<<768, 256, 0, stream>>>(qkvb, VT, ob);
  gemm_bt<EP_RES_F32, 2><<<dim3(12, 64), 256, 0, stream>>>(
      ob, wp, proj_b, x, x1, 8192, 768, 768);
  ln_kernel<<<8192, 256, 0, stream>>>(x1, ln2_w, ln2_b, h2);
  gemm_bt<EP_GELU_BF16, 4><<<dim3(24, 64), 256, 0, stream>>>(
      h2, wf1, fc1_b, nullptr, hm, 8192, 3072, 768);
  gemm_bt<EP_RES_F32, 2><<<dim3(12, 64), 256, 0, stream>>>(
      hm, wf2, fc2_b, x1, (float*)d_out, 8192, 768, 3072);
}